// Round 12
// baseline (191.446 us; speedup 1.0000x reference)
//
#include <hip/hip_runtime.h>
#include <math.h>

#define Bn 8
#define Tn 2048
#define En 1024
#define Hn 128
// sqrt(128) * log2(e): att scaled straight into exp2 domain (R20)
#define SQRTH_LOG2E (11.313708498984761f * 1.4426950408889634f)

typedef __attribute__((ext_vector_type(8))) short short8;
typedef __attribute__((ext_vector_type(8))) _Float16 half8;
typedef __attribute__((ext_vector_type(4))) short short4v;
typedef __attribute__((ext_vector_type(4))) float float4v;

#define MFMA16(a, b, c)  __builtin_amdgcn_mfma_f32_16x16x32_bf16((a), (b), (c), 0, 0, 0)
#define MFMA16F(a, b, c) __builtin_amdgcn_mfma_f32_16x16x32_f16((a), (b), (c), 0, 0, 0)

static __device__ __forceinline__ unsigned short f2bf(float f) {
    unsigned u = __float_as_uint(f);
    u += 0x7FFFu + ((u >> 16) & 1u);   // RNE
    return (unsigned short)(u >> 16);
}
static __device__ __forceinline__ unsigned short f2h(float f) {
    _Float16 h = (_Float16)f;          // RNE
    union { _Float16 v; unsigned short u; } c; c.v = h; return c.u;
}

// async global->LDS, 16 B per lane. LDS dest is wave-uniform base + lane*16.
static __device__ __forceinline__ void gll16(const unsigned short* g, unsigned short* l) {
    __builtin_amdgcn_global_load_lds(
        (const __attribute__((address_space(1))) unsigned int*)g,
        (__attribute__((address_space(3))) unsigned int*)l, 16, 0, 0);
}

// ---------------------------------------------------------------------------
// SWIZZLES (baked into GLOBAL layouts; all readers adjust):
//  - q/k rows (128 shorts = 16 x 16B blocks): block j of row t at j^(t&15).
//  - vtt rows (32 shorts = 4 blocks): block j of row h at j^((h>>1)&3).
//  - xt/wtt rows (32 shorts = 4 blocks): block j of row r at j^(r&3).
//
// R9 chunked partials; R11 single-buffer attn staging (230.7); R12 proj
// swizzle (218.9); R13 XCD batch affinity (208.7); R14/R15/R16/R19 schedule
// restructures ALL neutral-or-regressed -> with ~4.5 independent blocks/CU
// the convoy is already latency-hidden; attn kernels are at their
// schedule floor. R17 fp16 q/k (197.9); R18 fp16 x/W single-pass proj
// (177.8 = bank, absmax 0.078).
// R20: additive trims on the R18 structure: (1) wtrans merged into xconv
// (one fewer launch); (2) exp2-domain softmax (fold log2e into the att
// scale; every __expf loses its v_mul); (3) (m, il) fused to float2 (one
// 8B load per iter-half instead of two scalar loads). No structural or
// numeric-path changes beyond 1-2 ulp.
// ---------------------------------------------------------------------------

// ---------------------------------------------------------------------------
// Kernel 0 (merged): blocks 0..8191 convert x fp32 -> K-tiled fp16
// xt[mt][ks][64 r][32 k] (blocks swizzled j^(r&3)); blocks 8192..8383
// convert W fp32 -> wtt[z][ks][128 h][32 k] (blocks swizzled j^(h&3)).
// ---------------------------------------------------------------------------
__global__ __launch_bounds__(256) void prep_kernel(
    const float* __restrict__ x,
    const float* __restrict__ Wq, const float* __restrict__ Wk, const float* __restrict__ Wv,
    unsigned short* __restrict__ xt, unsigned short* __restrict__ wtt)
{
    if (blockIdx.x < 8192) {
        int g = blockIdx.x * 256 + threadIdx.x;   // 0..2097151
        int kc8 = g & 3;
        int rr = (g >> 2) & 63;
        int ks = (g >> 8) & 31;
        int mt = g >> 13;
        size_t src = ((size_t)mt * 64 + rr) * En + ks * 32 + kc8 * 8;
        float4v f0 = *(const float4v*)(x + src);
        float4v f1 = *(const float4v*)(x + src + 4);
        short8 h;
#pragma unroll
        for (int j = 0; j < 4; j++) {
            h[j] = (short)f2h(f0[j]);
            h[j + 4] = (short)f2h(f1[j]);
        }
        size_t d = (size_t)(g >> 2) * 32 + (size_t)(kc8 ^ (rr & 3)) * 8;
        *(short8*)(xt + d) = h;
    } else {
        int t = (blockIdx.x - 8192) * 256 + threadIdx.x;   // 0..49151
        int kc8 = t & 3;
        int hh = (t >> 2) & 127;
        int ks = (t >> 9) & 31;
        int z = t >> 14;
        const float* W = (z == 0) ? Wq : ((z == 1) ? Wk : Wv);
        short8 h8;
#pragma unroll
        for (int j = 0; j < 8; j++) {
            int e = ks * 32 + kc8 * 8 + j;
            h8[j] = (short)f2h(W[(size_t)e * Hn + hh]);
        }
        size_t d = (((size_t)z * 32 + ks) * 4096) + (size_t)hh * 32
                 + (size_t)(kc8 ^ (hh & 3)) * 8;
        *(short8*)(wtt + d) = h8;
    }
}

// ---------------------------------------------------------------------------
// Kernel 1: projections, single-pass fp16 LDS double-buffered GEMM.
// Staging 12 chunks/iter (A 4 + B 8), 3 per wave; LDS 24 KB. Swizzle-aware
// fragment reads (kg ^ (c15&3)). Epilogue: q/k fp16 row-swizzled; v bf16
// s-chunk-tiled vtt. (R18-verified, unchanged.)
// ---------------------------------------------------------------------------
__global__ __launch_bounds__(256) void proj_kernel(
    const unsigned short* __restrict__ xt, const unsigned short* __restrict__ wtt,
    unsigned short* __restrict__ qf, unsigned short* __restrict__ kf,
    unsigned short* __restrict__ vtt)
{
    __shared__ __align__(16) unsigned short lds[2][6144];  // 24 KB
    int z = blockIdx.y;
    int mt = blockIdx.x;                       // 0..255
    int tid = threadIdx.x;
    int wave = tid >> 6, lane = tid & 63;
    int c15 = lane & 15, kg = lane >> 4;
    int sb = c15 & 3;                          // read-swizzle selector
    int mrow = wave >> 1, ncol = wave & 1;     // 2x2 wave grid

    const unsigned short* A0 = xt + (size_t)mt * 32 * 2048;
    const unsigned short* B0 = wtt + (size_t)z * 32 * 4096;

    float4v acc[2][4];
#pragma unroll
    for (int i = 0; i < 2; i++)
#pragma unroll
        for (int j = 0; j < 4; j++) acc[i][j] = (float4v)0.0f;

    // hoisted staging cursors: 3 chunks/wave (12 total: A=4, B=8)
    const unsigned short* gcur[3];
    int lbo[3];
    int gstep[3];
#pragma unroll
    for (int i = 0; i < 3; i++) {
        int ch = wave * 3 + i;   // 0..11
        if (ch < 4) { gcur[i] = A0 + ch * 512;       lbo[i] = ch * 512;        gstep[i] = 2048; }
        else        { gcur[i] = B0 + (ch - 4) * 512; lbo[i] = 2048 + (ch - 4) * 512; gstep[i] = 4096; }
    }
    int lo8 = lane * 8;

    auto stage = [&](int buf) {
        unsigned short* Lb = lds[0] + buf * 6144;
#pragma unroll
        for (int i = 0; i < 3; i++) {
            gll16(gcur[i] + lo8, Lb + lbo[i] + lo8);
            gcur[i] += gstep[i];
        }
    };

    stage(0);

    for (int ks = 0; ks < 32; ks++) {
        __syncthreads();
        if (ks + 1 < 32) stage((ks + 1) & 1);
        const unsigned short* Lb = lds[ks & 1];

        half8 ah[2], bh[4];
#pragma unroll
        for (int mi = 0; mi < 2; mi++) {
            int row = mrow * 32 + mi * 16 + c15;
            ah[mi] = *(const half8*)(Lb + row * 32 + (kg ^ sb) * 8);
        }
#pragma unroll
        for (int ni = 0; ni < 4; ni++) {
            int row = ncol * 64 + ni * 16 + c15;
            bh[ni] = *(const half8*)(Lb + 2048 + row * 32 + (kg ^ sb) * 8);
        }
#pragma unroll
        for (int mi = 0; mi < 2; mi++)
#pragma unroll
            for (int ni = 0; ni < 4; ni++)
                acc[mi][ni] = MFMA16F(ah[mi], bh[ni], acc[mi][ni]);
    }

    if (z < 2) {
        unsigned short* oh = (z == 0) ? qf : kf;
#pragma unroll
        for (int mi = 0; mi < 2; mi++) {
#pragma unroll
            for (int ni = 0; ni < 4; ni++) {
                int h = ncol * 64 + ni * 16 + c15;
#pragma unroll
                for (int r = 0; r < 4; r++) {
                    int t = mt * 64 + mrow * 32 + mi * 16 + kg * 4 + r;
                    // swizzled: block (h>>3) of row t -> (h>>3) ^ (t&15)
                    size_t o = (size_t)t * Hn + (((h >> 3) ^ (t & 15)) << 3) + (h & 7);
                    oh[o] = f2h(acc[mi][ni][r]);        // fp16
                }
            }
        }
    } else {
        int b = mt >> 5;
#pragma unroll
        for (int mi = 0; mi < 2; mi++) {
            int t0 = (mt & 31) * 64 + mrow * 32 + mi * 16 + kg * 4;
            int sc = t0 >> 5, so = t0 & 31;
#pragma unroll
            for (int ni = 0; ni < 4; ni++) {
                int h = ncol * 64 + ni * 16 + c15;
                short4v pk;
#pragma unroll
                for (int r = 0; r < 4; r++) pk[r] = (short)f2bf(acc[mi][ni][r]);
                // swizzled: block (so>>3) of row h -> (so>>3) ^ ((h>>1)&3)
                int so2 = ((((so >> 3) ^ ((h >> 1) & 3))) << 3) | (so & 7);
                *(short4v*)(vtt + (((size_t)b * 64 + sc) * 128 + h) * 32 + so2) = pk;
            }
        }
    }
}

// ---------------------------------------------------------------------------
// Kernel 2: column softmax stats PARTIALS (base-2 domain). t-loop of column
// tile sj split into nch = ((31-sj)>>2)+1 even chunks (<=8 iters).
// Single-buffer staging (R18 form). grid (B, 144): XCD affinity.
// ---------------------------------------------------------------------------
__global__ __launch_bounds__(256) void stats_part_kernel(
    const unsigned short* __restrict__ qf, const unsigned short* __restrict__ kf,
    float* __restrict__ m_part, float* __restrict__ l_part)
{
    __shared__ __align__(16) unsigned short lds[4096];  // 8 KB, single buffer
    int tid = threadIdx.x;
    int wave = tid >> 6, lane = tid & 63;
    int c15 = lane & 15, kg = lane >> 4;
    int b = blockIdx.x;                       // XCD = b

    // map blockIdx.y -> (sj, ci); sj ascending = heavy first
    int rem = (int)blockIdx.y, sj, nch = 1;
    for (sj = 0; sj < 32; sj++) {
        nch = ((31 - sj) >> 2) + 1;
        if (rem < nch) break;
        rem -= nch;
    }
    int ci = rem;
    int c0 = 2 * sj;
    int len = 64 - c0;
    int cbase = len / nch, ext = len % nch;
    int cs = c0 + ci * cbase + (ci < ext ? ci : ext);
    int ce = cs + cbase + (ci < ext ? 1 : 0);

    int s_base = sj * 64 + wave * 16;

    // A fragments: wave's 16 k-rows (fp16); s&15 == c15
    half8 a[4];
    {
        int s = s_base + c15;
        const unsigned short* kr = kf + ((size_t)(b * Tn + s)) * Hn;
#pragma unroll
        for (int st = 0; st < 4; st++) {
            int off = ((st * 4 + kg) ^ c15) * 8;
            a[st] = *(const half8*)(kr + off);
        }
    }
    float m[4], l[4];
#pragma unroll
    for (int r = 0; r < 4; r++) { m[r] = -3.0e38f; l[r] = 0.0f; }

    auto stage = [&](int c) {
        const unsigned short* Qf = qf + ((size_t)b * Tn + c * 32) * Hn;
        int lo8 = lane * 8;
#pragma unroll
        for (int i = 0; i < 2; i++) {
            int ch = wave * 2 + i;   // 0..7
            gll16(Qf + ch * 512 + lo8, lds + ch * 512 + lo8);
        }
    };

    for (int c = cs; c < ce; c++) {
        stage(c);
        __syncthreads();   // stage complete
#pragma unroll
        for (int half = 0; half < 2; half++) {
            int t16 = c * 32 + half * 16;
            int tl = half * 16 + c15;
            float4v a1 = (float4v)0.0f;
#pragma unroll
            for (int st = 0; st < 4; st++) {
                // swizzled block ((st*4+kg) ^ (t&15)); t&15 == c15
                int off = tl * 128 + ((st * 4 + kg) ^ c15) * 8;
                half8 bh = *(const half8*)(lds + off);
                a1 = MFMA16F(a[st], bh, a1);
            }
            int t = t16 + c15;
#pragma unroll
            for (int r = 0; r < 4; r++) {
                float attv = a1[r] * SQRTH_LOG2E;      // base-2 domain
                int s_row = s_base + kg * 4 + r;
                bool valid = (t >= s_row);
                float cand = valid ? attv : -3.0e38f;
                float mn = fmaxf(m[r], cand);
                l[r] = l[r] * exp2f(m[r] - mn) + (valid ? exp2f(attv - mn) : 0.0f);
                m[r] = mn;
            }
        }
        __syncthreads();   // all reads done before next stage overwrites
    }
    // merge t-subsets across the 16 lanes sharing kg
#pragma unroll
    for (int mask = 1; mask < 16; mask <<= 1) {
#pragma unroll
        for (int r = 0; r < 4; r++) {
            float mo = __shfl_xor(m[r], mask);
            float lo2 = __shfl_xor(l[r], mask);
            float mn = fmaxf(m[r], mo);
            l[r] = l[r] * exp2f(m[r] - mn) + lo2 * exp2f(mo - mn);
            m[r] = mn;
        }
    }
    if (c15 == 0) {
#pragma unroll
        for (int r = 0; r < 4; r++) {
            int sl = wave * 16 + kg * 4 + r;           // 0..63 within tile
            size_t d = ((((size_t)b * 32 + sj) * 8 + ci) * 64) + sl;
            m_part[d] = m[r];
            l_part[d] = l[r];
        }
    }
}

// ---------------------------------------------------------------------------
// Kernel 2b: merge stats partials -> fused float2 ml_st (m2, il).
// ---------------------------------------------------------------------------
__global__ __launch_bounds__(256) void stats_combine_kernel(
    const float* __restrict__ m_part, const float* __restrict__ l_part,
    float2* __restrict__ ml_st)
{
    int g = blockIdx.x * 256 + threadIdx.x;   // 0..16383
    int s = g & 2047, b = g >> 11;
    int sj = s >> 6, sl = s & 63;
    int nch = ((31 - sj) >> 2) + 1;
    size_t base = (((size_t)b * 32 + sj) * 8) * 64 + sl;
    float M = m_part[base];
    float L = l_part[base];
    for (int ci = 1; ci < nch; ci++) {
        float mi = m_part[base + (size_t)ci * 64];
        float li = l_part[base + (size_t)ci * 64];
        float mn = fmaxf(M, mi);
        L = L * exp2f(M - mn) + li * exp2f(mi - mn);
        M = mn;
    }
    float2 ml; ml.x = M; ml.y = 1.0f / L;
    ml_st[(size_t)b * Tn + s] = ml;
}

// ---------------------------------------------------------------------------
// Kernel 3: output PARTIALS (base-2 domain). s-loop of row tile tj split
// into nch = (tj>>2)+1 even chunks (<=8 iters). Single-buffer staging
// (R18 form), fp16 QK + bf16 PV. grid (B, 144): XCD affinity.
// ---------------------------------------------------------------------------
__global__ __launch_bounds__(256) void out_part_kernel(
    const unsigned short* __restrict__ qf, const unsigned short* __restrict__ kf,
    const unsigned short* __restrict__ vtt,
    const float2* __restrict__ ml_st,
    float* __restrict__ part_out)
{
    __shared__ __align__(16) unsigned short lds[8192];       // 16 KB, single
    __shared__ __align__(16) unsigned short pbuf[4][16][40]; // 5 KB
    int tid = threadIdx.x;
    int wave = tid >> 6, lane = tid & 63;
    int c15 = lane & 15, kg = lane >> 4;
    int b = blockIdx.x;                       // XCD = b

    // map blockIdx.y -> (tj, ci); tj descending = heavy first
    int rem = (int)blockIdx.y, tj, nch = 1;
    for (tj = 31; tj >= 0; tj--) {
        nch = (tj >> 2) + 1;
        if (rem < nch) break;
        rem -= nch;
    }
    int ci = rem;
    int len = 2 * tj + 2;
    int cbase = len / nch, ext = len % nch;
    int cs = ci * cbase + (ci < ext ? ci : ext);
    int ce = cs + cbase + (ci < ext ? 1 : 0);

    int t_base = tj * 64 + wave * 16;

    // A fragments: wave's 16 q-rows (fp16); t&15 == c15
    half8 qa[4];
    {
        int t = t_base + c15;
        const unsigned short* qr = qf + ((size_t)(b * Tn + t)) * Hn;
#pragma unroll
        for (int st = 0; st < 4; st++) {
            int off = ((st * 4 + kg) ^ c15) * 8;
            qa[st] = *(const half8*)(qr + off);
        }
    }
    float4v oacc[8];
#pragma unroll
    for (int i = 0; i < 8; i++) oacc[i] = (float4v)0.0f;

    auto stage = [&](int c) {
        const unsigned short* Kf = kf + ((size_t)b * Tn + c * 32) * Hn;
        const unsigned short* Vv = vtt + ((size_t)b * 64 + c) * (128 * 32);
        int lo8 = lane * 8;
#pragma unroll
        for (int i = 0; i < 4; i++) {
            int ch = wave * 4 + i;   // 0..15
            const unsigned short* g;
            unsigned short* ld;
            if (ch < 8) { g = Kf + ch * 512;       ld = lds + ch * 512; }
            else        { g = Vv + (ch - 8) * 512; ld = lds + 4096 + (ch - 8) * 512; }
            gll16(g + lo8, ld + lo8);
        }
    };

    for (int c = cs; c < ce; c++) {
        stage(c);
        __syncthreads();   // stage complete
#pragma unroll
        for (int half = 0; half < 2; half++) {
            int s16 = c * 32 + half * 16;
            int sl = half * 16 + c15;
            float4v a1 = (float4v)0.0f;
#pragma unroll
            for (int st = 0; st < 4; st++) {
                // swizzled block ((st*4+kg) ^ (s&15)); s&15 == c15
                int off = sl * 128 + ((st * 4 + kg) ^ c15) * 8;
                half8 bh = *(const half8*)(lds + off);
                a1 = MFMA16F(qa[st], bh, a1);
            }
            float2 mlv = ml_st[b * Tn + s16 + c15];    // fused (m2, il)
#pragma unroll
            for (int r = 0; r < 4; r++) {
                int t = t_base + kg * 4 + r;
                float attv = a1[r] * SQRTH_LOG2E;      // base-2 domain
                // clamp: att <= column max for true data (ULP-exact safety)
                float earg = fminf(attv - mlv.x, 0.0f);
                float p = (t >= s16 + c15) ? exp2f(earg) * mlv.y : 0.0f;
                pbuf[wave][kg * 4 + r][c15 + half * 16] = f2bf(p);
            }
        }
        // C-layout -> A-layout via LDS (wave-internal, DS pipe in-order)
        short8 pa = *(const short8*)&pbuf[wave][c15][kg * 8];
#pragma unroll
        for (int nt = 0; nt < 8; nt++) {
            // vtt row h = nt*16+c15; swizzled block kg ^ ((h>>1)&3),
            // (h>>1)&3 == (c15>>1)&3 since nt*16 is a multiple of 8 in h>>1
            int voff = (nt * 16 + c15) * 32 + ((kg ^ ((c15 >> 1) & 3)) * 8);
            short8 vb = *(const short8*)(lds + 4096 + voff);
            oacc[nt] = MFMA16(pa, vb, oacc[nt]);
        }
        __syncthreads();   // all reads done before next stage overwrites
    }
    // partial tile store: part[b][tj][ci][t_local 64][h 128]
    float* po = part_out + ((((size_t)b * 32 + tj) * 8 + ci) * 64) * 128;
#pragma unroll
    for (int nt = 0; nt < 8; nt++) {
        int h = nt * 16 + c15;
#pragma unroll
        for (int r = 0; r < 4; r++) {
            int tl = wave * 16 + kg * 4 + r;
            po[(size_t)tl * 128 + h] = oacc[nt][r];
        }
    }
}

// ---------------------------------------------------------------------------
// Kernel 3b: sum output partials -> out. 2M floats, float4 loads/stores.
// ---------------------------------------------------------------------------
__global__ __launch_bounds__(256) void out_combine_kernel(
    const float* __restrict__ part_out, float* __restrict__ out)
{
    int g = blockIdx.x * 256 + threadIdx.x;   // 0..524287 (float4 units)
    int h4 = g & 31;
    int t = (g >> 5) & 2047;
    int b = g >> 16;
    int tj = t >> 6, tl = t & 63;
    int nch = (tj >> 2) + 1;
    const float4v* p = (const float4v*)(part_out
        + ((((size_t)b * 32 + tj) * 8) * 64 + tl) * 128) + h4;
    float4v acc = p[0];
    for (int ci = 1; ci < nch; ci++) acc += p[(size_t)ci * 2048];  // slot = 8192 floats
    *((float4v*)(out + ((size_t)b * Tn + t) * Hn) + h4) = acc;
}

// ---------------------------------------------------------------------------
extern "C" void kernel_launch(void* const* d_in, const int* in_sizes, int n_in,
                              void* d_out, int out_size, void* d_ws, size_t ws_size,
                              hipStream_t stream)
{
    (void)in_sizes; (void)n_in; (void)out_size; (void)ws_size;
    const float* x  = (const float*)d_in[0];
    const float* Wk = (const float*)d_in[1];
    const float* Wq = (const float*)d_in[2];
    const float* Wv = (const float*)d_in[3];
    float* out = (float*)d_out;

    const size_t NQ = (size_t)Bn * Tn * Hn;        // 2,097,152
    const size_t NX = (size_t)Bn * Tn * En;        // 16,777,216
    unsigned short* qf  = (unsigned short*)d_ws;   // fp16 q
    unsigned short* qlo = qf + NQ;                 // unused (kept layout)
    unsigned short* kf  = qlo + NQ;                // fp16 k
    unsigned short* klo = kf + NQ;                 // unused (kept layout)
    unsigned short* vtt  = klo + NQ;
    unsigned short* xt   = vtt + NQ;               // fp16 xt
    unsigned short* xt_lo = xt + NX;               // unused (kept layout)
    unsigned short* wtt  = xt_lo + NX;             // fp16 wtt
    unsigned short* wtt_lo = wtt + (size_t)3 * Hn * En;  // unused region
    float2* ml_st = (float2*)(wtt_lo + (size_t)3 * Hn * En);  // fused (m, il)
    // total ws use: ~89.4 MB — identical extent to the validated R7 layout

    // Dead-after-proj aliases:
    //  part_out = xt region: 8*32*8*64*128 fp32 = 67.1 MB == sizeof(xt+xt_lo)
    //  m_part/l_part = wtt regions: 8*32*8*64 fp32 = 512 KB each (<= 768 KB)
    float* part_out = (float*)xt;
    float* m_part   = (float*)wtt;
    float* l_part   = (float*)wtt_lo;

    prep_kernel<<<dim3(8384), 256, 0, stream>>>(x, Wq, Wk, Wv, xt, wtt);
    proj_kernel<<<dim3(256, 3), 256, 0, stream>>>(xt, wtt, qf, kf, vtt);
    stats_part_kernel<<<dim3(Bn, 144), 256, 0, stream>>>(qf, kf, m_part, l_part);
    stats_combine_kernel<<<dim3(64), 256, 0, stream>>>(m_part, l_part, ml_st);
    out_part_kernel<<<dim3(Bn, 144), 256, 0, stream>>>(qf, kf, vtt,
                                                       ml_st, part_out);
    out_combine_kernel<<<dim3(2048), 256, 0, stream>>>(part_out, out);
}

// Round 13
// 178.823 us; speedup vs baseline: 1.0706x; 1.0706x over previous
//
#include <hip/hip_runtime.h>
#include <math.h>

#define Bn 8
#define Tn 2048
#define En 1024
#define Hn 128
#define SQRTH 11.313708498984761f

typedef __attribute__((ext_vector_type(8))) short short8;
typedef __attribute__((ext_vector_type(8))) _Float16 half8;
typedef __attribute__((ext_vector_type(4))) short short4v;
typedef __attribute__((ext_vector_type(4))) float float4v;

#define MFMA16(a, b, c)  __builtin_amdgcn_mfma_f32_16x16x32_bf16((a), (b), (c), 0, 0, 0)
#define MFMA16F(a, b, c) __builtin_amdgcn_mfma_f32_16x16x32_f16((a), (b), (c), 0, 0, 0)

static __device__ __forceinline__ unsigned short f2bf(float f) {
    unsigned u = __float_as_uint(f);
    u += 0x7FFFu + ((u >> 16) & 1u);   // RNE
    return (unsigned short)(u >> 16);
}
static __device__ __forceinline__ unsigned short f2h(float f) {
    _Float16 h = (_Float16)f;          // RNE
    union { _Float16 v; unsigned short u; } c; c.v = h; return c.u;
}

// async global->LDS, 16 B per lane. LDS dest is wave-uniform base + lane*16.
static __device__ __forceinline__ void gll16(const unsigned short* g, unsigned short* l) {
    __builtin_amdgcn_global_load_lds(
        (const __attribute__((address_space(1))) unsigned int*)g,
        (__attribute__((address_space(3))) unsigned int*)l, 16, 0, 0);
}

// ---------------------------------------------------------------------------
// SWIZZLES (baked into GLOBAL layouts; all readers adjust):
//  - q/k rows (128 shorts = 16 x 16B blocks): block j of row t at j^(t&15).
//  - vtt rows (32 shorts = 4 blocks): block j of row h at j^((h>>1)&3).
//  - xt/wtt rows (32 shorts = 4 blocks): block j of row r at j^(r&3).
//
// Ladder: R9 chunked partials; R11 single-buffer attn staging (230.7);
// R12 proj swizzle (218.9); R13 XCD batch affinity (208.7); R17 fp16 q/k
// single-pass QK^T (197.9); R18 fp16 x/W single-pass proj (177.8 = BEST,
// absmax 0.078).
// Non-wins (all reverted): R14 8-wave blocks (222.3 — independent 256-thr
// block streams are the latency hider); R15 direct-L2 reads (243 —
// scattered loads serialize; bulk DMA staging is right); R16 dbuf 54 KB
// (223 — occupancy /2); R19 dbuf 37 KB (180.8 — neutral); R20 exp2f/
// prep-merge/float2 trims (191.4 — exp2f is the PRECISE libm path, not
// v_exp; __expf is the fast intrinsic).
// R21: revert to R18 verbatim. Plateau: remaining time is per-launch
// latency + serial LDS/VALU work; no counter shows a saturated resource;
// three scheduling idioms and micro-trims all failed to compress it.
// ---------------------------------------------------------------------------

// ---------------------------------------------------------------------------
// Kernel 0: W (E,H) fp32 -> K-tiled fp16 wtt[z][ks][128 h][32 k],
// 16B blocks swizzled j^(h&3).
// ---------------------------------------------------------------------------
__global__ __launch_bounds__(256) void wtrans_kernel(
    const float* __restrict__ Wq, const float* __restrict__ Wk, const float* __restrict__ Wv,
    unsigned short* __restrict__ wtt)
{
    int t = blockIdx.x * 256 + threadIdx.x;   // 0..49151
    int kc8 = t & 3;
    int hh = (t >> 2) & 127;
    int ks = (t >> 9) & 31;
    int z = t >> 14;
    const float* W = (z == 0) ? Wq : ((z == 1) ? Wk : Wv);
    short8 h8;
#pragma unroll
    for (int j = 0; j < 8; j++) {
        int e = ks * 32 + kc8 * 8 + j;
        h8[j] = (short)f2h(W[(size_t)e * Hn + hh]);
    }
    size_t d = (((size_t)z * 32 + ks) * 4096) + (size_t)hh * 32
             + (size_t)(kc8 ^ (hh & 3)) * 8;            // R12 swizzle
    *(short8*)(wtt + d) = h8;
}

// ---------------------------------------------------------------------------
// Kernel 0b: x fp32 -> K-tiled fp16 xt[mt][ks][64 r][32 k],
// 16B blocks swizzled j^(r&3).
// ---------------------------------------------------------------------------
__global__ __launch_bounds__(256) void xconv_kernel(
    const float* __restrict__ x, unsigned short* __restrict__ xt)
{
    int g = blockIdx.x * 256 + threadIdx.x;   // 0..2097151
    int kc8 = g & 3;
    int rr = (g >> 2) & 63;
    int ks = (g >> 8) & 31;
    int mt = g >> 13;
    size_t src = ((size_t)mt * 64 + rr) * En + ks * 32 + kc8 * 8;
    float4v f0 = *(const float4v*)(x + src);
    float4v f1 = *(const float4v*)(x + src + 4);
    short8 h;
#pragma unroll
    for (int j = 0; j < 4; j++) {
        h[j] = (short)f2h(f0[j]);
        h[j + 4] = (short)f2h(f1[j]);
    }
    size_t d = (size_t)(g >> 2) * 32 + (size_t)(kc8 ^ (rr & 3)) * 8;  // R12
    *(short8*)(xt + d) = h;
}

// ---------------------------------------------------------------------------
// Kernel 1: projections, single-pass fp16 LDS double-buffered GEMM.
// Staging 12 chunks/iter (A 4 + B 8), 3 per wave; LDS 24 KB. Swizzle-aware
// fragment reads (kg ^ (c15&3)). Epilogue: q/k fp16 row-swizzled; v bf16
// s-chunk-tiled vtt. (R18-verified.)
// ---------------------------------------------------------------------------
__global__ __launch_bounds__(256) void proj_kernel(
    const unsigned short* __restrict__ xt, const unsigned short* __restrict__ wtt,
    unsigned short* __restrict__ qf, unsigned short* __restrict__ kf,
    unsigned short* __restrict__ vtt)
{
    __shared__ __align__(16) unsigned short lds[2][6144];  // 24 KB
    int z = blockIdx.y;
    int mt = blockIdx.x;                       // 0..255
    int tid = threadIdx.x;
    int wave = tid >> 6, lane = tid & 63;
    int c15 = lane & 15, kg = lane >> 4;
    int sb = c15 & 3;                          // read-swizzle selector
    int mrow = wave >> 1, ncol = wave & 1;     // 2x2 wave grid

    const unsigned short* A0 = xt + (size_t)mt * 32 * 2048;
    const unsigned short* B0 = wtt + (size_t)z * 32 * 4096;

    float4v acc[2][4];
#pragma unroll
    for (int i = 0; i < 2; i++)
#pragma unroll
        for (int j = 0; j < 4; j++) acc[i][j] = (float4v)0.0f;

    // hoisted staging cursors: 3 chunks/wave (12 total: A=4, B=8)
    const unsigned short* gcur[3];
    int lbo[3];
    int gstep[3];
#pragma unroll
    for (int i = 0; i < 3; i++) {
        int ch = wave * 3 + i;   // 0..11
        if (ch < 4) { gcur[i] = A0 + ch * 512;       lbo[i] = ch * 512;        gstep[i] = 2048; }
        else        { gcur[i] = B0 + (ch - 4) * 512; lbo[i] = 2048 + (ch - 4) * 512; gstep[i] = 4096; }
    }
    int lo8 = lane * 8;

    auto stage = [&](int buf) {
        unsigned short* Lb = lds[0] + buf * 6144;
#pragma unroll
        for (int i = 0; i < 3; i++) {
            gll16(gcur[i] + lo8, Lb + lbo[i] + lo8);
            gcur[i] += gstep[i];
        }
    };

    stage(0);

    for (int ks = 0; ks < 32; ks++) {
        __syncthreads();
        if (ks + 1 < 32) stage((ks + 1) & 1);
        const unsigned short* Lb = lds[ks & 1];

        half8 ah[2], bh[4];
#pragma unroll
        for (int mi = 0; mi < 2; mi++) {
            int row = mrow * 32 + mi * 16 + c15;
            ah[mi] = *(const half8*)(Lb + row * 32 + (kg ^ sb) * 8);
        }
#pragma unroll
        for (int ni = 0; ni < 4; ni++) {
            int row = ncol * 64 + ni * 16 + c15;
            bh[ni] = *(const half8*)(Lb + 2048 + row * 32 + (kg ^ sb) * 8);
        }
#pragma unroll
        for (int mi = 0; mi < 2; mi++)
#pragma unroll
            for (int ni = 0; ni < 4; ni++)
                acc[mi][ni] = MFMA16F(ah[mi], bh[ni], acc[mi][ni]);
    }

    if (z < 2) {
        unsigned short* oh = (z == 0) ? qf : kf;
#pragma unroll
        for (int mi = 0; mi < 2; mi++) {
#pragma unroll
            for (int ni = 0; ni < 4; ni++) {
                int h = ncol * 64 + ni * 16 + c15;
#pragma unroll
                for (int r = 0; r < 4; r++) {
                    int t = mt * 64 + mrow * 32 + mi * 16 + kg * 4 + r;
                    // swizzled: block (h>>3) of row t -> (h>>3) ^ (t&15)
                    size_t o = (size_t)t * Hn + (((h >> 3) ^ (t & 15)) << 3) + (h & 7);
                    oh[o] = f2h(acc[mi][ni][r]);        // fp16
                }
            }
        }
    } else {
        int b = mt >> 5;
#pragma unroll
        for (int mi = 0; mi < 2; mi++) {
            int t0 = (mt & 31) * 64 + mrow * 32 + mi * 16 + kg * 4;
            int sc = t0 >> 5, so = t0 & 31;
#pragma unroll
            for (int ni = 0; ni < 4; ni++) {
                int h = ncol * 64 + ni * 16 + c15;
                short4v pk;
#pragma unroll
                for (int r = 0; r < 4; r++) pk[r] = (short)f2bf(acc[mi][ni][r]);
                // swizzled: block (so>>3) of row h -> (so>>3) ^ ((h>>1)&3)
                int so2 = ((((so >> 3) ^ ((h >> 1) & 3))) << 3) | (so & 7);
                *(short4v*)(vtt + (((size_t)b * 64 + sc) * 128 + h) * 32 + so2) = pk;
            }
        }
    }
}

// ---------------------------------------------------------------------------
// Kernel 2: column softmax stats PARTIALS. t-loop of column tile sj split
// into nch = ((31-sj)>>2)+1 even chunks (<=8 iters). Single-buffer staging,
// fp16 single-pass QK. grid (B, 144): XCD affinity. (R17/R18-verified.)
// ---------------------------------------------------------------------------
__global__ __launch_bounds__(256) void stats_part_kernel(
    const unsigned short* __restrict__ qf, const unsigned short* __restrict__ kf,
    float* __restrict__ m_part, float* __restrict__ l_part)
{
    __shared__ __align__(16) unsigned short lds[4096];  // 8 KB, single buffer
    int tid = threadIdx.x;
    int wave = tid >> 6, lane = tid & 63;
    int c15 = lane & 15, kg = lane >> 4;
    int b = blockIdx.x;                       // XCD = b

    // map blockIdx.y -> (sj, ci); sj ascending = heavy first
    int rem = (int)blockIdx.y, sj, nch = 1;
    for (sj = 0; sj < 32; sj++) {
        nch = ((31 - sj) >> 2) + 1;
        if (rem < nch) break;
        rem -= nch;
    }
    int ci = rem;
    int c0 = 2 * sj;
    int len = 64 - c0;
    int cbase = len / nch, ext = len % nch;
    int cs = c0 + ci * cbase + (ci < ext ? ci : ext);
    int ce = cs + cbase + (ci < ext ? 1 : 0);

    int s_base = sj * 64 + wave * 16;

    // A fragments: wave's 16 k-rows (fp16); s&15 == c15
    half8 a[4];
    {
        int s = s_base + c15;
        const unsigned short* kr = kf + ((size_t)(b * Tn + s)) * Hn;
#pragma unroll
        for (int st = 0; st < 4; st++) {
            int off = ((st * 4 + kg) ^ c15) * 8;
            a[st] = *(const half8*)(kr + off);
        }
    }
    float m[4], l[4];
#pragma unroll
    for (int r = 0; r < 4; r++) { m[r] = -3.0e38f; l[r] = 0.0f; }

    auto stage = [&](int c) {
        const unsigned short* Qf = qf + ((size_t)b * Tn + c * 32) * Hn;
        int lo8 = lane * 8;
#pragma unroll
        for (int i = 0; i < 2; i++) {
            int ch = wave * 2 + i;   // 0..7
            gll16(Qf + ch * 512 + lo8, lds + ch * 512 + lo8);
        }
    };

    for (int c = cs; c < ce; c++) {
        stage(c);
        __syncthreads();   // stage complete
#pragma unroll
        for (int half = 0; half < 2; half++) {
            int t16 = c * 32 + half * 16;
            int tl = half * 16 + c15;
            float4v a1 = (float4v)0.0f;
#pragma unroll
            for (int st = 0; st < 4; st++) {
                // swizzled block ((st*4+kg) ^ (t&15)); t&15 == c15
                int off = tl * 128 + ((st * 4 + kg) ^ c15) * 8;
                half8 bh = *(const half8*)(lds + off);
                a1 = MFMA16F(a[st], bh, a1);
            }
            int t = t16 + c15;
#pragma unroll
            for (int r = 0; r < 4; r++) {
                float attv = a1[r] * SQRTH;
                int s_row = s_base + kg * 4 + r;
                bool valid = (t >= s_row);
                float cand = valid ? attv : -3.0e38f;
                float mn = fmaxf(m[r], cand);
                l[r] = l[r] * __expf(m[r] - mn) + (valid ? __expf(attv - mn) : 0.0f);
                m[r] = mn;
            }
        }
        __syncthreads();   // all reads done before next stage overwrites
    }
    // merge t-subsets across the 16 lanes sharing kg
#pragma unroll
    for (int mask = 1; mask < 16; mask <<= 1) {
#pragma unroll
        for (int r = 0; r < 4; r++) {
            float mo = __shfl_xor(m[r], mask);
            float lo2 = __shfl_xor(l[r], mask);
            float mn = fmaxf(m[r], mo);
            l[r] = l[r] * __expf(m[r] - mn) + lo2 * __expf(mo - mn);
            m[r] = mn;
        }
    }
    if (c15 == 0) {
#pragma unroll
        for (int r = 0; r < 4; r++) {
            int sl = wave * 16 + kg * 4 + r;           // 0..63 within tile
            size_t d = ((((size_t)b * 32 + sj) * 8 + ci) * 64) + sl;
            m_part[d] = m[r];
            l_part[d] = l[r];
        }
    }
}

// ---------------------------------------------------------------------------
// Kernel 2b: merge stats partials -> (m_st, il_st). 16384 columns.
// ---------------------------------------------------------------------------
__global__ __launch_bounds__(256) void stats_combine_kernel(
    const float* __restrict__ m_part, const float* __restrict__ l_part,
    float* __restrict__ m_st, float* __restrict__ il_st)
{
    int g = blockIdx.x * 256 + threadIdx.x;   // 0..16383
    int s = g & 2047, b = g >> 11;
    int sj = s >> 6, sl = s & 63;
    int nch = ((31 - sj) >> 2) + 1;
    size_t base = (((size_t)b * 32 + sj) * 8) * 64 + sl;
    float M = m_part[base];
    float L = l_part[base];
    for (int ci = 1; ci < nch; ci++) {
        float mi = m_part[base + (size_t)ci * 64];
        float li = l_part[base + (size_t)ci * 64];
        float mn = fmaxf(M, mi);
        L = L * __expf(M - mn) + li * __expf(mi - mn);
        M = mn;
    }
    m_st[(size_t)b * Tn + s] = M;
    il_st[(size_t)b * Tn + s] = 1.0f / L;
}

// ---------------------------------------------------------------------------
// Kernel 3: output PARTIALS. s-loop of row tile tj split into nch =
// (tj>>2)+1 even chunks (<=8 iters). Single-buffer staging, fp16 QK +
// bf16 PV. grid (B, 144): XCD affinity. (R17/R18-verified.)
// ---------------------------------------------------------------------------
__global__ __launch_bounds__(256) void out_part_kernel(
    const unsigned short* __restrict__ qf, const unsigned short* __restrict__ kf,
    const unsigned short* __restrict__ vtt,
    const float* __restrict__ m_st, const float* __restrict__ il_st,
    float* __restrict__ part_out)
{
    __shared__ __align__(16) unsigned short lds[8192];       // 16 KB, single
    __shared__ __align__(16) unsigned short pbuf[4][16][40]; // 5 KB
    int tid = threadIdx.x;
    int wave = tid >> 6, lane = tid & 63;
    int c15 = lane & 15, kg = lane >> 4;
    int b = blockIdx.x;                       // XCD = b

    // map blockIdx.y -> (tj, ci); tj descending = heavy first
    int rem = (int)blockIdx.y, tj, nch = 1;
    for (tj = 31; tj >= 0; tj--) {
        nch = (tj >> 2) + 1;
        if (rem < nch) break;
        rem -= nch;
    }
    int ci = rem;
    int len = 2 * tj + 2;
    int cbase = len / nch, ext = len % nch;
    int cs = ci * cbase + (ci < ext ? ci : ext);
    int ce = cs + cbase + (ci < ext ? 1 : 0);

    int t_base = tj * 64 + wave * 16;

    // A fragments: wave's 16 q-rows (fp16); t&15 == c15
    half8 qa[4];
    {
        int t = t_base + c15;
        const unsigned short* qr = qf + ((size_t)(b * Tn + t)) * Hn;
#pragma unroll
        for (int st = 0; st < 4; st++) {
            int off = ((st * 4 + kg) ^ c15) * 8;
            qa[st] = *(const half8*)(qr + off);
        }
    }
    float4v oacc[8];
#pragma unroll
    for (int i = 0; i < 8; i++) oacc[i] = (float4v)0.0f;

    auto stage = [&](int c) {
        const unsigned short* Kf = kf + ((size_t)b * Tn + c * 32) * Hn;
        const unsigned short* Vv = vtt + ((size_t)b * 64 + c) * (128 * 32);
        int lo8 = lane * 8;
#pragma unroll
        for (int i = 0; i < 4; i++) {
            int ch = wave * 4 + i;   // 0..15
            const unsigned short* g;
            unsigned short* ld;
            if (ch < 8) { g = Kf + ch * 512;       ld = lds + ch * 512; }
            else        { g = Vv + (ch - 8) * 512; ld = lds + 4096 + (ch - 8) * 512; }
            gll16(g + lo8, ld + lo8);
        }
    };

    for (int c = cs; c < ce; c++) {
        stage(c);
        __syncthreads();   // stage complete
#pragma unroll
        for (int half = 0; half < 2; half++) {
            int s16 = c * 32 + half * 16;
            int sl = half * 16 + c15;
            float4v a1 = (float4v)0.0f;
#pragma unroll
            for (int st = 0; st < 4; st++) {
                // swizzled block ((st*4+kg) ^ (s&15)); s&15 == c15
                int off = sl * 128 + ((st * 4 + kg) ^ c15) * 8;
                half8 bh = *(const half8*)(lds + off);
                a1 = MFMA16F(qa[st], bh, a1);
            }
            float msv = m_st[b * Tn + s16 + c15];
            float ilv = il_st[b * Tn + s16 + c15];
#pragma unroll
            for (int r = 0; r < 4; r++) {
                int t = t_base + kg * 4 + r;
                float attv = a1[r] * SQRTH;
                // clamp: att <= column max for true data (ULP-exact safety)
                float earg = fminf(attv - msv, 0.0f);
                float p = (t >= s16 + c15) ? __expf(earg) * ilv : 0.0f;
                pbuf[wave][kg * 4 + r][c15 + half * 16] = f2bf(p);
            }
        }
        // C-layout -> A-layout via LDS (wave-internal, DS pipe in-order)
        short8 pa = *(const short8*)&pbuf[wave][c15][kg * 8];
#pragma unroll
        for (int nt = 0; nt < 8; nt++) {
            // vtt row h = nt*16+c15; swizzled block kg ^ ((h>>1)&3),
            // (h>>1)&3 == (c15>>1)&3 since nt*16 is a multiple of 8 in h>>1
            int voff = (nt * 16 + c15) * 32 + ((kg ^ ((c15 >> 1) & 3)) * 8);
            short8 vb = *(const short8*)(lds + 4096 + voff);
            oacc[nt] = MFMA16(pa, vb, oacc[nt]);
        }
        __syncthreads();   // all reads done before next stage overwrites
    }
    // partial tile store: part[b][tj][ci][t_local 64][h 128]
    float* po = part_out + ((((size_t)b * 32 + tj) * 8 + ci) * 64) * 128;
#pragma unroll
    for (int nt = 0; nt < 8; nt++) {
        int h = nt * 16 + c15;
#pragma unroll
        for (int r = 0; r < 4; r++) {
            int tl = wave * 16 + kg * 4 + r;
            po[(size_t)tl * 128 + h] = oacc[nt][r];
        }
    }
}

// ---------------------------------------------------------------------------
// Kernel 3b: sum output partials -> out. 2M floats, float4 loads/stores.
// ---------------------------------------------------------------------------
__global__ __launch_bounds__(256) void out_combine_kernel(
    const float* __restrict__ part_out, float* __restrict__ out)
{
    int g = blockIdx.x * 256 + threadIdx.x;   // 0..524287 (float4 units)
    int h4 = g & 31;
    int t = (g >> 5) & 2047;
    int b = g >> 16;
    int tj = t >> 6, tl = t & 63;
    int nch = (tj >> 2) + 1;
    const float4v* p = (const float4v*)(part_out
        + ((((size_t)b * 32 + tj) * 8) * 64 + tl) * 128) + h4;
    float4v acc = p[0];
    for (int ci = 1; ci < nch; ci++) acc += p[(size_t)ci * 2048];  // slot = 8192 floats
    *((float4v*)(out + ((size_t)b * Tn + t) * Hn) + h4) = acc;
}

// ---------------------------------------------------------------------------
extern "C" void kernel_launch(void* const* d_in, const int* in_sizes, int n_in,
                              void* d_out, int out_size, void* d_ws, size_t ws_size,
                              hipStream_t stream)
{
    (void)in_sizes; (void)n_in; (void)out_size; (void)ws_size;
    const float* x  = (const float*)d_in[0];
    const float* Wk = (const float*)d_in[1];
    const float* Wq = (const float*)d_in[2];
    const float* Wv = (const float*)d_in[3];
    float* out = (float*)d_out;

    const size_t NQ = (size_t)Bn * Tn * Hn;        // 2,097,152
    const size_t NX = (size_t)Bn * Tn * En;        // 16,777,216
    unsigned short* qf  = (unsigned short*)d_ws;   // fp16 q
    unsigned short* qlo = qf + NQ;                 // unused (kept layout)
    unsigned short* kf  = qlo + NQ;                // fp16 k
    unsigned short* klo = kf + NQ;                 // unused (kept layout)
    unsigned short* vtt  = klo + NQ;
    unsigned short* xt   = vtt + NQ;               // fp16 xt
    unsigned short* xt_lo = xt + NX;               // unused (kept layout)
    unsigned short* wtt  = xt_lo + NX;             // fp16 wtt
    unsigned short* wtt_lo = wtt + (size_t)3 * Hn * En;  // unused region
    float* m_st  = (float*)(wtt_lo + (size_t)3 * Hn * En);
    float* il_st = m_st + (size_t)Bn * Tn;
    // total ws use: ~89.4 MB — identical extent to the validated R7 layout

    // Dead-after-proj aliases:
    //  part_out = xt region: 8*32*8*64*128 fp32 = 67.1 MB == sizeof(xt+xt_lo)
    //  m_part/l_part = wtt regions: 8*32*8*64 fp32 = 512 KB each (<= 768 KB)
    float* part_out = (float*)xt;
    float* m_part   = (float*)wtt;
    float* l_part   = (float*)wtt_lo;

    wtrans_kernel<<<dim3(192), 256, 0, stream>>>(Wq, Wk, Wv, wtt);
    xconv_kernel<<<dim3(8192), 256, 0, stream>>>(x, xt);
    proj_kernel<<<dim3(256, 3), 256, 0, stream>>>(xt, wtt, qf, kf, vtt);
    stats_part_kernel<<<dim3(Bn, 144), 256, 0, stream>>>(qf, kf, m_part, l_part);
    stats_combine_kernel<<<dim3(64), 256, 0, stream>>>(m_part, l_part, m_st, il_st);
    out_part_kernel<<<dim3(Bn, 144), 256, 0, stream>>>(qf, kf, vtt,
                                                       m_st, il_st, part_out);
    out_combine_kernel<<<dim3(2048), 256, 0, stream>>>(part_out, out);
}

// Round 14
// 174.156 us; speedup vs baseline: 1.0993x; 1.0268x over previous
//
#include <hip/hip_runtime.h>
#include <math.h>

#define Bn 8
#define Tn 2048
#define En 1024
#define Hn 128
// sqrt(128) * log2(e): att scaled straight into exp2 domain (R22)
#define SQRTH_LOG2E (11.313708498984761f * 1.4426950408889634f)

typedef __attribute__((ext_vector_type(8))) short short8;
typedef __attribute__((ext_vector_type(8))) _Float16 half8;
typedef __attribute__((ext_vector_type(4))) short short4v;
typedef __attribute__((ext_vector_type(4))) float float4v;

#define MFMA16(a, b, c)  __builtin_amdgcn_mfma_f32_16x16x32_bf16((a), (b), (c), 0, 0, 0)
#define MFMA16F(a, b, c) __builtin_amdgcn_mfma_f32_16x16x32_f16((a), (b), (c), 0, 0, 0)
// raw v_exp_f32 — the HW instruction __expf uses AFTER its v_mul by log2e
#define EXP2(x) __builtin_amdgcn_exp2f(x)

static __device__ __forceinline__ unsigned short f2bf(float f) {
    unsigned u = __float_as_uint(f);
    u += 0x7FFFu + ((u >> 16) & 1u);   // RNE
    return (unsigned short)(u >> 16);
}
static __device__ __forceinline__ unsigned short f2h(float f) {
    _Float16 h = (_Float16)f;          // RNE
    union { _Float16 v; unsigned short u; } c; c.v = h; return c.u;
}

// async global->LDS, 16 B per lane. LDS dest is wave-uniform base + lane*16.
static __device__ __forceinline__ void gll16(const unsigned short* g, unsigned short* l) {
    __builtin_amdgcn_global_load_lds(
        (const __attribute__((address_space(1))) unsigned int*)g,
        (__attribute__((address_space(3))) unsigned int*)l, 16, 0, 0);
}

// ---------------------------------------------------------------------------
// SWIZZLES (baked into GLOBAL layouts; all readers adjust):
//  - q/k rows (128 shorts = 16 x 16B blocks): block j of row t at j^(t&15).
//  - vtt rows (32 shorts = 4 blocks): block j of row h at j^((h>>1)&3).
//  - xt/wtt rows (32 shorts = 4 blocks): block j of row r at j^(r&3).
//
// Ladder: R9 chunked partials; R11 single-buffer attn staging (230.7);
// R12 proj swizzle (218.9); R13 XCD batch affinity (208.7); R17 fp16 q/k
// single-pass QK^T (197.9); R18 fp16 x/W single-pass proj (177.8/178.8 =
// bank, absmax 0.078).
// Non-wins: R14 wide blocks; R15 direct-L2; R16/R19 dbuf-in-attn; R20
// trims with libm exp2f (191.4 — but PASSED: all three trims are
// correctness-verified; only exp2f's precise path was slow).
// R22: R20's verified source with exp2f -> __builtin_amdgcn_exp2f (raw
// v_exp_f32). Each exponential loses its v_mul; prep-merge saves a launch;
// float2 (m,il) fuses two scalar loads. Only delta from a passed run.
// ---------------------------------------------------------------------------

// ---------------------------------------------------------------------------
// Kernel 0 (merged): blocks 0..8191 convert x fp32 -> K-tiled fp16
// xt[mt][ks][64 r][32 k] (blocks swizzled j^(r&3)); blocks 8192..8383
// convert W fp32 -> wtt[z][ks][128 h][32 k] (blocks swizzled j^(h&3)).
// ---------------------------------------------------------------------------
__global__ __launch_bounds__(256) void prep_kernel(
    const float* __restrict__ x,
    const float* __restrict__ Wq, const float* __restrict__ Wk, const float* __restrict__ Wv,
    unsigned short* __restrict__ xt, unsigned short* __restrict__ wtt)
{
    if (blockIdx.x < 8192) {
        int g = blockIdx.x * 256 + threadIdx.x;   // 0..2097151
        int kc8 = g & 3;
        int rr = (g >> 2) & 63;
        int ks = (g >> 8) & 31;
        int mt = g >> 13;
        size_t src = ((size_t)mt * 64 + rr) * En + ks * 32 + kc8 * 8;
        float4v f0 = *(const float4v*)(x + src);
        float4v f1 = *(const float4v*)(x + src + 4);
        short8 h;
#pragma unroll
        for (int j = 0; j < 4; j++) {
            h[j] = (short)f2h(f0[j]);
            h[j + 4] = (short)f2h(f1[j]);
        }
        size_t d = (size_t)(g >> 2) * 32 + (size_t)(kc8 ^ (rr & 3)) * 8;
        *(short8*)(xt + d) = h;
    } else {
        int t = (blockIdx.x - 8192) * 256 + threadIdx.x;   // 0..49151
        int kc8 = t & 3;
        int hh = (t >> 2) & 127;
        int ks = (t >> 9) & 31;
        int z = t >> 14;
        const float* W = (z == 0) ? Wq : ((z == 1) ? Wk : Wv);
        short8 h8;
#pragma unroll
        for (int j = 0; j < 8; j++) {
            int e = ks * 32 + kc8 * 8 + j;
            h8[j] = (short)f2h(W[(size_t)e * Hn + hh]);
        }
        size_t d = (((size_t)z * 32 + ks) * 4096) + (size_t)hh * 32
                 + (size_t)(kc8 ^ (hh & 3)) * 8;
        *(short8*)(wtt + d) = h8;
    }
}

// ---------------------------------------------------------------------------
// Kernel 1: projections, single-pass fp16 LDS double-buffered GEMM.
// Staging 12 chunks/iter (A 4 + B 8), 3 per wave; LDS 24 KB. Swizzle-aware
// fragment reads (kg ^ (c15&3)). Epilogue: q/k fp16 row-swizzled; v bf16
// s-chunk-tiled vtt. (R18-verified, unchanged.)
// ---------------------------------------------------------------------------
__global__ __launch_bounds__(256) void proj_kernel(
    const unsigned short* __restrict__ xt, const unsigned short* __restrict__ wtt,
    unsigned short* __restrict__ qf, unsigned short* __restrict__ kf,
    unsigned short* __restrict__ vtt)
{
    __shared__ __align__(16) unsigned short lds[2][6144];  // 24 KB
    int z = blockIdx.y;
    int mt = blockIdx.x;                       // 0..255
    int tid = threadIdx.x;
    int wave = tid >> 6, lane = tid & 63;
    int c15 = lane & 15, kg = lane >> 4;
    int sb = c15 & 3;                          // read-swizzle selector
    int mrow = wave >> 1, ncol = wave & 1;     // 2x2 wave grid

    const unsigned short* A0 = xt + (size_t)mt * 32 * 2048;
    const unsigned short* B0 = wtt + (size_t)z * 32 * 4096;

    float4v acc[2][4];
#pragma unroll
    for (int i = 0; i < 2; i++)
#pragma unroll
        for (int j = 0; j < 4; j++) acc[i][j] = (float4v)0.0f;

    // hoisted staging cursors: 3 chunks/wave (12 total: A=4, B=8)
    const unsigned short* gcur[3];
    int lbo[3];
    int gstep[3];
#pragma unroll
    for (int i = 0; i < 3; i++) {
        int ch = wave * 3 + i;   // 0..11
        if (ch < 4) { gcur[i] = A0 + ch * 512;       lbo[i] = ch * 512;        gstep[i] = 2048; }
        else        { gcur[i] = B0 + (ch - 4) * 512; lbo[i] = 2048 + (ch - 4) * 512; gstep[i] = 4096; }
    }
    int lo8 = lane * 8;

    auto stage = [&](int buf) {
        unsigned short* Lb = lds[0] + buf * 6144;
#pragma unroll
        for (int i = 0; i < 3; i++) {
            gll16(gcur[i] + lo8, Lb + lbo[i] + lo8);
            gcur[i] += gstep[i];
        }
    };

    stage(0);

    for (int ks = 0; ks < 32; ks++) {
        __syncthreads();
        if (ks + 1 < 32) stage((ks + 1) & 1);
        const unsigned short* Lb = lds[ks & 1];

        half8 ah[2], bh[4];
#pragma unroll
        for (int mi = 0; mi < 2; mi++) {
            int row = mrow * 32 + mi * 16 + c15;
            ah[mi] = *(const half8*)(Lb + row * 32 + (kg ^ sb) * 8);
        }
#pragma unroll
        for (int ni = 0; ni < 4; ni++) {
            int row = ncol * 64 + ni * 16 + c15;
            bh[ni] = *(const half8*)(Lb + 2048 + row * 32 + (kg ^ sb) * 8);
        }
#pragma unroll
        for (int mi = 0; mi < 2; mi++)
#pragma unroll
            for (int ni = 0; ni < 4; ni++)
                acc[mi][ni] = MFMA16F(ah[mi], bh[ni], acc[mi][ni]);
    }

    if (z < 2) {
        unsigned short* oh = (z == 0) ? qf : kf;
#pragma unroll
        for (int mi = 0; mi < 2; mi++) {
#pragma unroll
            for (int ni = 0; ni < 4; ni++) {
                int h = ncol * 64 + ni * 16 + c15;
#pragma unroll
                for (int r = 0; r < 4; r++) {
                    int t = mt * 64 + mrow * 32 + mi * 16 + kg * 4 + r;
                    // swizzled: block (h>>3) of row t -> (h>>3) ^ (t&15)
                    size_t o = (size_t)t * Hn + (((h >> 3) ^ (t & 15)) << 3) + (h & 7);
                    oh[o] = f2h(acc[mi][ni][r]);        // fp16
                }
            }
        }
    } else {
        int b = mt >> 5;
#pragma unroll
        for (int mi = 0; mi < 2; mi++) {
            int t0 = (mt & 31) * 64 + mrow * 32 + mi * 16 + kg * 4;
            int sc = t0 >> 5, so = t0 & 31;
#pragma unroll
            for (int ni = 0; ni < 4; ni++) {
                int h = ncol * 64 + ni * 16 + c15;
                short4v pk;
#pragma unroll
                for (int r = 0; r < 4; r++) pk[r] = (short)f2bf(acc[mi][ni][r]);
                // swizzled: block (so>>3) of row h -> (so>>3) ^ ((h>>1)&3)
                int so2 = ((((so >> 3) ^ ((h >> 1) & 3))) << 3) | (so & 7);
                *(short4v*)(vtt + (((size_t)b * 64 + sc) * 128 + h) * 32 + so2) = pk;
            }
        }
    }
}

// ---------------------------------------------------------------------------
// Kernel 2: column softmax stats PARTIALS (base-2 domain, raw v_exp).
// t-loop of column tile sj split into nch = ((31-sj)>>2)+1 even chunks
// (<=8 iters). Single-buffer staging. grid (B, 144): XCD affinity.
// ---------------------------------------------------------------------------
__global__ __launch_bounds__(256) void stats_part_kernel(
    const unsigned short* __restrict__ qf, const unsigned short* __restrict__ kf,
    float* __restrict__ m_part, float* __restrict__ l_part)
{
    __shared__ __align__(16) unsigned short lds[4096];  // 8 KB, single buffer
    int tid = threadIdx.x;
    int wave = tid >> 6, lane = tid & 63;
    int c15 = lane & 15, kg = lane >> 4;
    int b = blockIdx.x;                       // XCD = b

    // map blockIdx.y -> (sj, ci); sj ascending = heavy first
    int rem = (int)blockIdx.y, sj, nch = 1;
    for (sj = 0; sj < 32; sj++) {
        nch = ((31 - sj) >> 2) + 1;
        if (rem < nch) break;
        rem -= nch;
    }
    int ci = rem;
    int c0 = 2 * sj;
    int len = 64 - c0;
    int cbase = len / nch, ext = len % nch;
    int cs = c0 + ci * cbase + (ci < ext ? ci : ext);
    int ce = cs + cbase + (ci < ext ? 1 : 0);

    int s_base = sj * 64 + wave * 16;

    // A fragments: wave's 16 k-rows (fp16); s&15 == c15
    half8 a[4];
    {
        int s = s_base + c15;
        const unsigned short* kr = kf + ((size_t)(b * Tn + s)) * Hn;
#pragma unroll
        for (int st = 0; st < 4; st++) {
            int off = ((st * 4 + kg) ^ c15) * 8;
            a[st] = *(const half8*)(kr + off);
        }
    }
    float m[4], l[4];
#pragma unroll
    for (int r = 0; r < 4; r++) { m[r] = -3.0e38f; l[r] = 0.0f; }

    auto stage = [&](int c) {
        const unsigned short* Qf = qf + ((size_t)b * Tn + c * 32) * Hn;
        int lo8 = lane * 8;
#pragma unroll
        for (int i = 0; i < 2; i++) {
            int ch = wave * 2 + i;   // 0..7
            gll16(Qf + ch * 512 + lo8, lds + ch * 512 + lo8);
        }
    };

    for (int c = cs; c < ce; c++) {
        stage(c);
        __syncthreads();   // stage complete
#pragma unroll
        for (int half = 0; half < 2; half++) {
            int t16 = c * 32 + half * 16;
            int tl = half * 16 + c15;
            float4v a1 = (float4v)0.0f;
#pragma unroll
            for (int st = 0; st < 4; st++) {
                // swizzled block ((st*4+kg) ^ (t&15)); t&15 == c15
                int off = tl * 128 + ((st * 4 + kg) ^ c15) * 8;
                half8 bh = *(const half8*)(lds + off);
                a1 = MFMA16F(a[st], bh, a1);
            }
            int t = t16 + c15;
#pragma unroll
            for (int r = 0; r < 4; r++) {
                float attv = a1[r] * SQRTH_LOG2E;      // base-2 domain
                int s_row = s_base + kg * 4 + r;
                bool valid = (t >= s_row);
                float cand = valid ? attv : -3.0e38f;
                float mn = fmaxf(m[r], cand);
                l[r] = l[r] * EXP2(m[r] - mn) + (valid ? EXP2(attv - mn) : 0.0f);
                m[r] = mn;
            }
        }
        __syncthreads();   // all reads done before next stage overwrites
    }
    // merge t-subsets across the 16 lanes sharing kg
#pragma unroll
    for (int mask = 1; mask < 16; mask <<= 1) {
#pragma unroll
        for (int r = 0; r < 4; r++) {
            float mo = __shfl_xor(m[r], mask);
            float lo2 = __shfl_xor(l[r], mask);
            float mn = fmaxf(m[r], mo);
            l[r] = l[r] * EXP2(m[r] - mn) + lo2 * EXP2(mo - mn);
            m[r] = mn;
        }
    }
    if (c15 == 0) {
#pragma unroll
        for (int r = 0; r < 4; r++) {
            int sl = wave * 16 + kg * 4 + r;           // 0..63 within tile
            size_t d = ((((size_t)b * 32 + sj) * 8 + ci) * 64) + sl;
            m_part[d] = m[r];
            l_part[d] = l[r];
        }
    }
}

// ---------------------------------------------------------------------------
// Kernel 2b: merge stats partials -> fused float2 ml_st (m2, il).
// ---------------------------------------------------------------------------
__global__ __launch_bounds__(256) void stats_combine_kernel(
    const float* __restrict__ m_part, const float* __restrict__ l_part,
    float2* __restrict__ ml_st)
{
    int g = blockIdx.x * 256 + threadIdx.x;   // 0..16383
    int s = g & 2047, b = g >> 11;
    int sj = s >> 6, sl = s & 63;
    int nch = ((31 - sj) >> 2) + 1;
    size_t base = (((size_t)b * 32 + sj) * 8) * 64 + sl;
    float M = m_part[base];
    float L = l_part[base];
    for (int ci = 1; ci < nch; ci++) {
        float mi = m_part[base + (size_t)ci * 64];
        float li = l_part[base + (size_t)ci * 64];
        float mn = fmaxf(M, mi);
        L = L * EXP2(M - mn) + li * EXP2(mi - mn);
        M = mn;
    }
    float2 ml; ml.x = M; ml.y = 1.0f / L;
    ml_st[(size_t)b * Tn + s] = ml;
}

// ---------------------------------------------------------------------------
// Kernel 3: output PARTIALS (base-2 domain, raw v_exp). s-loop of row tile
// tj split into nch = (tj>>2)+1 even chunks (<=8 iters). Single-buffer
// staging, fp16 QK + bf16 PV. grid (B, 144): XCD affinity.
// ---------------------------------------------------------------------------
__global__ __launch_bounds__(256) void out_part_kernel(
    const unsigned short* __restrict__ qf, const unsigned short* __restrict__ kf,
    const unsigned short* __restrict__ vtt,
    const float2* __restrict__ ml_st,
    float* __restrict__ part_out)
{
    __shared__ __align__(16) unsigned short lds[8192];       // 16 KB, single
    __shared__ __align__(16) unsigned short pbuf[4][16][40]; // 5 KB
    int tid = threadIdx.x;
    int wave = tid >> 6, lane = tid & 63;
    int c15 = lane & 15, kg = lane >> 4;
    int b = blockIdx.x;                       // XCD = b

    // map blockIdx.y -> (tj, ci); tj descending = heavy first
    int rem = (int)blockIdx.y, tj, nch = 1;
    for (tj = 31; tj >= 0; tj--) {
        nch = (tj >> 2) + 1;
        if (rem < nch) break;
        rem -= nch;
    }
    int ci = rem;
    int len = 2 * tj + 2;
    int cbase = len / nch, ext = len % nch;
    int cs = ci * cbase + (ci < ext ? ci : ext);
    int ce = cs + cbase + (ci < ext ? 1 : 0);

    int t_base = tj * 64 + wave * 16;

    // A fragments: wave's 16 q-rows (fp16); t&15 == c15
    half8 qa[4];
    {
        int t = t_base + c15;
        const unsigned short* qr = qf + ((size_t)(b * Tn + t)) * Hn;
#pragma unroll
        for (int st = 0; st < 4; st++) {
            int off = ((st * 4 + kg) ^ c15) * 8;
            qa[st] = *(const half8*)(qr + off);
        }
    }
    float4v oacc[8];
#pragma unroll
    for (int i = 0; i < 8; i++) oacc[i] = (float4v)0.0f;

    auto stage = [&](int c) {
        const unsigned short* Kf = kf + ((size_t)b * Tn + c * 32) * Hn;
        const unsigned short* Vv = vtt + ((size_t)b * 64 + c) * (128 * 32);
        int lo8 = lane * 8;
#pragma unroll
        for (int i = 0; i < 4; i++) {
            int ch = wave * 4 + i;   // 0..15
            const unsigned short* g;
            unsigned short* ld;
            if (ch < 8) { g = Kf + ch * 512;       ld = lds + ch * 512; }
            else        { g = Vv + (ch - 8) * 512; ld = lds + 4096 + (ch - 8) * 512; }
            gll16(g + lo8, ld + lo8);
        }
    };

    for (int c = cs; c < ce; c++) {
        stage(c);
        __syncthreads();   // stage complete
#pragma unroll
        for (int half = 0; half < 2; half++) {
            int s16 = c * 32 + half * 16;
            int sl = half * 16 + c15;
            float4v a1 = (float4v)0.0f;
#pragma unroll
            for (int st = 0; st < 4; st++) {
                // swizzled block ((st*4+kg) ^ (s&15)); s&15 == c15
                int off = sl * 128 + ((st * 4 + kg) ^ c15) * 8;
                half8 bh = *(const half8*)(lds + off);
                a1 = MFMA16F(qa[st], bh, a1);
            }
            float2 mlv = ml_st[b * Tn + s16 + c15];    // fused (m2, il)
#pragma unroll
            for (int r = 0; r < 4; r++) {
                int t = t_base + kg * 4 + r;
                float attv = a1[r] * SQRTH_LOG2E;      // base-2 domain
                // clamp: att <= column max for true data (ULP-exact safety)
                float earg = fminf(attv - mlv.x, 0.0f);
                float p = (t >= s16 + c15) ? EXP2(earg) * mlv.y : 0.0f;
                pbuf[wave][kg * 4 + r][c15 + half * 16] = f2bf(p);
            }
        }
        // C-layout -> A-layout via LDS (wave-internal, DS pipe in-order)
        short8 pa = *(const short8*)&pbuf[wave][c15][kg * 8];
#pragma unroll
        for (int nt = 0; nt < 8; nt++) {
            // vtt row h = nt*16+c15; swizzled block kg ^ ((h>>1)&3),
            // (h>>1)&3 == (c15>>1)&3 since nt*16 is a multiple of 8 in h>>1
            int voff = (nt * 16 + c15) * 32 + ((kg ^ ((c15 >> 1) & 3)) * 8);
            short8 vb = *(const short8*)(lds + 4096 + voff);
            oacc[nt] = MFMA16(pa, vb, oacc[nt]);
        }
        __syncthreads();   // all reads done before next stage overwrites
    }
    // partial tile store: part[b][tj][ci][t_local 64][h 128]
    float* po = part_out + ((((size_t)b * 32 + tj) * 8 + ci) * 64) * 128;
#pragma unroll
    for (int nt = 0; nt < 8; nt++) {
        int h = nt * 16 + c15;
#pragma unroll
        for (int r = 0; r < 4; r++) {
            int tl = wave * 16 + kg * 4 + r;
            po[(size_t)tl * 128 + h] = oacc[nt][r];
        }
    }
}

// ---------------------------------------------------------------------------
// Kernel 3b: sum output partials -> out. 2M floats, float4 loads/stores.
// ---------------------------------------------------------------------------
__global__ __launch_bounds__(256) void out_combine_kernel(
    const float* __restrict__ part_out, float* __restrict__ out)
{
    int g = blockIdx.x * 256 + threadIdx.x;   // 0..524287 (float4 units)
    int h4 = g & 31;
    int t = (g >> 5) & 2047;
    int b = g >> 16;
    int tj = t >> 6, tl = t & 63;
    int nch = (tj >> 2) + 1;
    const float4v* p = (const float4v*)(part_out
        + ((((size_t)b * 32 + tj) * 8) * 64 + tl) * 128) + h4;
    float4v acc = p[0];
    for (int ci = 1; ci < nch; ci++) acc += p[(size_t)ci * 2048];  // slot = 8192 floats
    *((float4v*)(out + ((size_t)b * Tn + t) * Hn) + h4) = acc;
}

// ---------------------------------------------------------------------------
extern "C" void kernel_launch(void* const* d_in, const int* in_sizes, int n_in,
                              void* d_out, int out_size, void* d_ws, size_t ws_size,
                              hipStream_t stream)
{
    (void)in_sizes; (void)n_in; (void)out_size; (void)ws_size;
    const float* x  = (const float*)d_in[0];
    const float* Wk = (const float*)d_in[1];
    const float* Wq = (const float*)d_in[2];
    const float* Wv = (const float*)d_in[3];
    float* out = (float*)d_out;

    const size_t NQ = (size_t)Bn * Tn * Hn;        // 2,097,152
    const size_t NX = (size_t)Bn * Tn * En;        // 16,777,216
    unsigned short* qf  = (unsigned short*)d_ws;   // fp16 q
    unsigned short* qlo = qf + NQ;                 // unused (kept layout)
    unsigned short* kf  = qlo + NQ;                // fp16 k
    unsigned short* klo = kf + NQ;                 // unused (kept layout)
    unsigned short* vtt  = klo + NQ;
    unsigned short* xt   = vtt + NQ;               // fp16 xt
    unsigned short* xt_lo = xt + NX;               // unused (kept layout)
    unsigned short* wtt  = xt_lo + NX;             // fp16 wtt
    unsigned short* wtt_lo = wtt + (size_t)3 * Hn * En;  // unused region
    float2* ml_st = (float2*)(wtt_lo + (size_t)3 * Hn * En);  // fused (m2, il)
    // total ws use: ~89.4 MB — identical extent to the validated R7 layout

    // Dead-after-proj aliases:
    //  part_out = xt region: 8*32*8*64*128 fp32 = 67.1 MB == sizeof(xt+xt_lo)
    //  m_part/l_part = wtt regions: 8*32*8*64 fp32 = 512 KB each (<= 768 KB)
    float* part_out = (float*)xt;
    float* m_part   = (float*)wtt;
    float* l_part   = (float*)wtt_lo;

    prep_kernel<<<dim3(8384), 256, 0, stream>>>(x, Wq, Wk, Wv, xt, wtt);
    proj_kernel<<<dim3(256, 3), 256, 0, stream>>>(xt, wtt, qf, kf, vtt);
    stats_part_kernel<<<dim3(Bn, 144), 256, 0, stream>>>(qf, kf, m_part, l_part);
    stats_combine_kernel<<<dim3(64), 256, 0, stream>>>(m_part, l_part, ml_st);
    out_part_kernel<<<dim3(Bn, 144), 256, 0, stream>>>(qf, kf, vtt,
                                                       ml_st, part_out);
    out_combine_kernel<<<dim3(2048), 256, 0, stream>>>(part_out, out);
}

// Round 15
// 168.677 us; speedup vs baseline: 1.1350x; 1.0325x over previous
//
#include <hip/hip_runtime.h>
#include <math.h>

#define Bn 8
#define Tn 2048
#define En 1024
#define Hn 128
// sqrt(128) * log2(e): att scaled straight into exp2 domain
#define SQRTH_LOG2E (11.313708498984761f * 1.4426950408889634f)

typedef __attribute__((ext_vector_type(8))) short short8;
typedef __attribute__((ext_vector_type(8))) _Float16 half8;
typedef __attribute__((ext_vector_type(4))) short short4v;
typedef __attribute__((ext_vector_type(4))) float float4v;

#define MFMA16(a, b, c)  __builtin_amdgcn_mfma_f32_16x16x32_bf16((a), (b), (c), 0, 0, 0)
#define MFMA16F(a, b, c) __builtin_amdgcn_mfma_f32_16x16x32_f16((a), (b), (c), 0, 0, 0)
// raw v_exp_f32 (verified R22: the fast HW path; libm exp2f is NOT)
#define EXP2(x) __builtin_amdgcn_exp2f(x)

static __device__ __forceinline__ unsigned short f2bf(float f) {
    unsigned u = __float_as_uint(f);
    u += 0x7FFFu + ((u >> 16) & 1u);   // RNE
    return (unsigned short)(u >> 16);
}
static __device__ __forceinline__ unsigned short f2h(float f) {
    _Float16 h = (_Float16)f;          // RNE
    union { _Float16 v; unsigned short u; } c; c.v = h; return c.u;
}

// async global->LDS, 16 B per lane. LDS dest is wave-uniform base + lane*16.
static __device__ __forceinline__ void gll16(const unsigned short* g, unsigned short* l) {
    __builtin_amdgcn_global_load_lds(
        (const __attribute__((address_space(1))) unsigned int*)g,
        (__attribute__((address_space(3))) unsigned int*)l, 16, 0, 0);
}

// ---------------------------------------------------------------------------
// SWIZZLES (baked into GLOBAL layouts; all readers adjust):
//  - q/k rows (128 shorts = 16 x 16B blocks): block j of row t at j^(t&15).
//  - vtt rows (32 shorts = 4 blocks): block j of row h at j^((h>>1)&3).
//  - xt/wtt rows (32 shorts = 4 blocks): block j of row r at j^(r&3).
//
// Ladder: R9 chunked partials; R11 single-buffer attn staging (230.7);
// R12 proj swizzle (218.9); R13 XCD batch affinity (208.7); R17 fp16 q/k
// (197.9); R18 fp16 x/W single-pass proj (177.8); R22 prep-merge + base-2
// softmax via raw v_exp + float2 ml (174.2 = bank, absmax 0.078).
// Non-wins: R14 wide blocks; R15 direct-L2; R16/R19 dbuf-in-attn; R20
// libm exp2f.
// R23: (1) stats_combine FUSED into out_part prologue — each block
// combines its own <=256 columns from m/l parts (XCD-local L2 after R13
// affinity) into a 2 KB LDS mlbuf; one fewer launch + dependency edge.
// (2) stats update fused across halves: 3 exp2 per r/iter instead of 4
// (one rescale); exact-arithmetic-identical, valid-guards preserved.
// ---------------------------------------------------------------------------

// ---------------------------------------------------------------------------
// Kernel 0 (merged): blocks 0..8191 convert x fp32 -> K-tiled fp16
// xt[mt][ks][64 r][32 k] (blocks swizzled j^(r&3)); blocks 8192..8383
// convert W fp32 -> wtt[z][ks][128 h][32 k] (blocks swizzled j^(h&3)).
// ---------------------------------------------------------------------------
__global__ __launch_bounds__(256) void prep_kernel(
    const float* __restrict__ x,
    const float* __restrict__ Wq, const float* __restrict__ Wk, const float* __restrict__ Wv,
    unsigned short* __restrict__ xt, unsigned short* __restrict__ wtt)
{
    if (blockIdx.x < 8192) {
        int g = blockIdx.x * 256 + threadIdx.x;   // 0..2097151
        int kc8 = g & 3;
        int rr = (g >> 2) & 63;
        int ks = (g >> 8) & 31;
        int mt = g >> 13;
        size_t src = ((size_t)mt * 64 + rr) * En + ks * 32 + kc8 * 8;
        float4v f0 = *(const float4v*)(x + src);
        float4v f1 = *(const float4v*)(x + src + 4);
        short8 h;
#pragma unroll
        for (int j = 0; j < 4; j++) {
            h[j] = (short)f2h(f0[j]);
            h[j + 4] = (short)f2h(f1[j]);
        }
        size_t d = (size_t)(g >> 2) * 32 + (size_t)(kc8 ^ (rr & 3)) * 8;
        *(short8*)(xt + d) = h;
    } else {
        int t = (blockIdx.x - 8192) * 256 + threadIdx.x;   // 0..49151
        int kc8 = t & 3;
        int hh = (t >> 2) & 127;
        int ks = (t >> 9) & 31;
        int z = t >> 14;
        const float* W = (z == 0) ? Wq : ((z == 1) ? Wk : Wv);
        short8 h8;
#pragma unroll
        for (int j = 0; j < 8; j++) {
            int e = ks * 32 + kc8 * 8 + j;
            h8[j] = (short)f2h(W[(size_t)e * Hn + hh]);
        }
        size_t d = (((size_t)z * 32 + ks) * 4096) + (size_t)hh * 32
                 + (size_t)(kc8 ^ (hh & 3)) * 8;
        *(short8*)(wtt + d) = h8;
    }
}

// ---------------------------------------------------------------------------
// Kernel 1: projections, single-pass fp16 LDS double-buffered GEMM.
// Staging 12 chunks/iter (A 4 + B 8), 3 per wave; LDS 24 KB. Swizzle-aware
// fragment reads (kg ^ (c15&3)). Epilogue: q/k fp16 row-swizzled; v bf16
// s-chunk-tiled vtt. (R18-verified, unchanged.)
// ---------------------------------------------------------------------------
__global__ __launch_bounds__(256) void proj_kernel(
    const unsigned short* __restrict__ xt, const unsigned short* __restrict__ wtt,
    unsigned short* __restrict__ qf, unsigned short* __restrict__ kf,
    unsigned short* __restrict__ vtt)
{
    __shared__ __align__(16) unsigned short lds[2][6144];  // 24 KB
    int z = blockIdx.y;
    int mt = blockIdx.x;                       // 0..255
    int tid = threadIdx.x;
    int wave = tid >> 6, lane = tid & 63;
    int c15 = lane & 15, kg = lane >> 4;
    int sb = c15 & 3;                          // read-swizzle selector
    int mrow = wave >> 1, ncol = wave & 1;     // 2x2 wave grid

    const unsigned short* A0 = xt + (size_t)mt * 32 * 2048;
    const unsigned short* B0 = wtt + (size_t)z * 32 * 4096;

    float4v acc[2][4];
#pragma unroll
    for (int i = 0; i < 2; i++)
#pragma unroll
        for (int j = 0; j < 4; j++) acc[i][j] = (float4v)0.0f;

    // hoisted staging cursors: 3 chunks/wave (12 total: A=4, B=8)
    const unsigned short* gcur[3];
    int lbo[3];
    int gstep[3];
#pragma unroll
    for (int i = 0; i < 3; i++) {
        int ch = wave * 3 + i;   // 0..11
        if (ch < 4) { gcur[i] = A0 + ch * 512;       lbo[i] = ch * 512;        gstep[i] = 2048; }
        else        { gcur[i] = B0 + (ch - 4) * 512; lbo[i] = 2048 + (ch - 4) * 512; gstep[i] = 4096; }
    }
    int lo8 = lane * 8;

    auto stage = [&](int buf) {
        unsigned short* Lb = lds[0] + buf * 6144;
#pragma unroll
        for (int i = 0; i < 3; i++) {
            gll16(gcur[i] + lo8, Lb + lbo[i] + lo8);
            gcur[i] += gstep[i];
        }
    };

    stage(0);

    for (int ks = 0; ks < 32; ks++) {
        __syncthreads();
        if (ks + 1 < 32) stage((ks + 1) & 1);
        const unsigned short* Lb = lds[ks & 1];

        half8 ah[2], bh[4];
#pragma unroll
        for (int mi = 0; mi < 2; mi++) {
            int row = mrow * 32 + mi * 16 + c15;
            ah[mi] = *(const half8*)(Lb + row * 32 + (kg ^ sb) * 8);
        }
#pragma unroll
        for (int ni = 0; ni < 4; ni++) {
            int row = ncol * 64 + ni * 16 + c15;
            bh[ni] = *(const half8*)(Lb + 2048 + row * 32 + (kg ^ sb) * 8);
        }
#pragma unroll
        for (int mi = 0; mi < 2; mi++)
#pragma unroll
            for (int ni = 0; ni < 4; ni++)
                acc[mi][ni] = MFMA16F(ah[mi], bh[ni], acc[mi][ni]);
    }

    if (z < 2) {
        unsigned short* oh = (z == 0) ? qf : kf;
#pragma unroll
        for (int mi = 0; mi < 2; mi++) {
#pragma unroll
            for (int ni = 0; ni < 4; ni++) {
                int h = ncol * 64 + ni * 16 + c15;
#pragma unroll
                for (int r = 0; r < 4; r++) {
                    int t = mt * 64 + mrow * 32 + mi * 16 + kg * 4 + r;
                    // swizzled: block (h>>3) of row t -> (h>>3) ^ (t&15)
                    size_t o = (size_t)t * Hn + (((h >> 3) ^ (t & 15)) << 3) + (h & 7);
                    oh[o] = f2h(acc[mi][ni][r]);        // fp16
                }
            }
        }
    } else {
        int b = mt >> 5;
#pragma unroll
        for (int mi = 0; mi < 2; mi++) {
            int t0 = (mt & 31) * 64 + mrow * 32 + mi * 16 + kg * 4;
            int sc = t0 >> 5, so = t0 & 31;
#pragma unroll
            for (int ni = 0; ni < 4; ni++) {
                int h = ncol * 64 + ni * 16 + c15;
                short4v pk;
#pragma unroll
                for (int r = 0; r < 4; r++) pk[r] = (short)f2bf(acc[mi][ni][r]);
                // swizzled: block (so>>3) of row h -> (so>>3) ^ ((h>>1)&3)
                int so2 = ((((so >> 3) ^ ((h >> 1) & 3))) << 3) | (so & 7);
                *(short4v*)(vtt + (((size_t)b * 64 + sc) * 128 + h) * 32 + so2) = pk;
            }
        }
    }
}

// ---------------------------------------------------------------------------
// Kernel 2: column softmax stats PARTIALS (base-2 domain, raw v_exp).
// t-loop of column tile sj split into nch = ((31-sj)>>2)+1 even chunks
// (<=8 iters). Single-buffer staging. R23: both halves' att computed first,
// then ONE fused online update per r (3 exp2 instead of 4; exact-identical;
// valid-guards keep all-invalid lanes at l=0). grid (B, 144): XCD affinity.
// ---------------------------------------------------------------------------
__global__ __launch_bounds__(256) void stats_part_kernel(
    const unsigned short* __restrict__ qf, const unsigned short* __restrict__ kf,
    float* __restrict__ m_part, float* __restrict__ l_part)
{
    __shared__ __align__(16) unsigned short lds[4096];  // 8 KB, single buffer
    int tid = threadIdx.x;
    int wave = tid >> 6, lane = tid & 63;
    int c15 = lane & 15, kg = lane >> 4;
    int b = blockIdx.x;                       // XCD = b

    // map blockIdx.y -> (sj, ci); sj ascending = heavy first
    int rem = (int)blockIdx.y, sj, nch = 1;
    for (sj = 0; sj < 32; sj++) {
        nch = ((31 - sj) >> 2) + 1;
        if (rem < nch) break;
        rem -= nch;
    }
    int ci = rem;
    int c0 = 2 * sj;
    int len = 64 - c0;
    int cbase = len / nch, ext = len % nch;
    int cs = c0 + ci * cbase + (ci < ext ? ci : ext);
    int ce = cs + cbase + (ci < ext ? 1 : 0);

    int s_base = sj * 64 + wave * 16;

    // A fragments: wave's 16 k-rows (fp16); s&15 == c15
    half8 a[4];
    {
        int s = s_base + c15;
        const unsigned short* kr = kf + ((size_t)(b * Tn + s)) * Hn;
#pragma unroll
        for (int st = 0; st < 4; st++) {
            int off = ((st * 4 + kg) ^ c15) * 8;
            a[st] = *(const half8*)(kr + off);
        }
    }
    float m[4], l[4];
#pragma unroll
    for (int r = 0; r < 4; r++) { m[r] = -3.0e38f; l[r] = 0.0f; }

    auto stage = [&](int c) {
        const unsigned short* Qf = qf + ((size_t)b * Tn + c * 32) * Hn;
        int lo8 = lane * 8;
#pragma unroll
        for (int i = 0; i < 2; i++) {
            int ch = wave * 2 + i;   // 0..7
            gll16(Qf + ch * 512 + lo8, lds + ch * 512 + lo8);
        }
    };

    for (int c = cs; c < ce; c++) {
        stage(c);
        __syncthreads();   // stage complete
        float4v av[2];
#pragma unroll
        for (int half = 0; half < 2; half++) {
            int tl = half * 16 + c15;
            float4v a1 = (float4v)0.0f;
#pragma unroll
            for (int st = 0; st < 4; st++) {
                // swizzled block ((st*4+kg) ^ (t&15)); t&15 == c15
                int off = tl * 128 + ((st * 4 + kg) ^ c15) * 8;
                half8 bh = *(const half8*)(lds + off);
                a1 = MFMA16F(a[st], bh, a1);
            }
            av[half] = a1;
        }
        int t0 = c * 32 + c15;
        int t1 = c * 32 + 16 + c15;
#pragma unroll
        for (int r = 0; r < 4; r++) {
            int s_row = s_base + kg * 4 + r;
            float v0 = av[0][r] * SQRTH_LOG2E;     // base-2 domain
            float v1 = av[1][r] * SQRTH_LOG2E;
            bool val0 = (t0 >= s_row), val1 = (t1 >= s_row);
            float c0v = val0 ? v0 : -3.0e38f;
            float c1v = val1 ? v1 : -3.0e38f;
            float mn = fmaxf(m[r], fmaxf(c0v, c1v));
            l[r] = l[r] * EXP2(m[r] - mn)
                 + (val0 ? EXP2(v0 - mn) : 0.0f)
                 + (val1 ? EXP2(v1 - mn) : 0.0f);
            m[r] = mn;
        }
        __syncthreads();   // all reads done before next stage overwrites
    }
    // merge t-subsets across the 16 lanes sharing kg
#pragma unroll
    for (int mask = 1; mask < 16; mask <<= 1) {
#pragma unroll
        for (int r = 0; r < 4; r++) {
            float mo = __shfl_xor(m[r], mask);
            float lo2 = __shfl_xor(l[r], mask);
            float mn = fmaxf(m[r], mo);
            l[r] = l[r] * EXP2(m[r] - mn) + lo2 * EXP2(mo - mn);
            m[r] = mn;
        }
    }
    if (c15 == 0) {
#pragma unroll
        for (int r = 0; r < 4; r++) {
            int sl = wave * 16 + kg * 4 + r;           // 0..63 within tile
            size_t d = ((((size_t)b * 32 + sj) * 8 + ci) * 64) + sl;
            m_part[d] = m[r];
            l_part[d] = l[r];
        }
    }
}

// ---------------------------------------------------------------------------
// Kernel 3: output PARTIALS (base-2 domain, raw v_exp). s-loop of row tile
// tj split into nch = (tj>>2)+1 even chunks (<=8 iters). Single-buffer
// staging, fp16 QK + bf16 PV. R23: stats-combine FUSED into the prologue —
// each block combines its <=256 columns from m/l parts (same-XCD L2) into
// LDS mlbuf; the loop's first barrier orders it. grid (B, 144).
// ---------------------------------------------------------------------------
__global__ __launch_bounds__(256) void out_part_kernel(
    const unsigned short* __restrict__ qf, const unsigned short* __restrict__ kf,
    const unsigned short* __restrict__ vtt,
    const float* __restrict__ m_part, const float* __restrict__ l_part,
    float* __restrict__ part_out)
{
    __shared__ __align__(16) unsigned short lds[8192];       // 16 KB, single
    __shared__ __align__(16) unsigned short pbuf[4][16][40]; // 5 KB
    __shared__ float2 mlbuf[256];                            // 2 KB
    int tid = threadIdx.x;
    int wave = tid >> 6, lane = tid & 63;
    int c15 = lane & 15, kg = lane >> 4;
    int b = blockIdx.x;                       // XCD = b

    // map blockIdx.y -> (tj, ci); tj descending = heavy first
    int rem = (int)blockIdx.y, tj, nch = 1;
    for (tj = 31; tj >= 0; tj--) {
        nch = (tj >> 2) + 1;
        if (rem < nch) break;
        rem -= nch;
    }
    int ci = rem;
    int len = 2 * tj + 2;
    int cbase = len / nch, ext = len % nch;
    int cs = ci * cbase + (ci < ext ? ci : ext);
    int ce = cs + cbase + (ci < ext ? 1 : 0);

    // fused stats-combine for this block's columns [cs*32, ce*32)
    {
        int ncols = (ce - cs) * 32;                // <= 256
        if (tid < ncols) {
            int s = cs * 32 + tid;
            int sj2 = s >> 6, sl2 = s & 63;
            int nchs = ((31 - sj2) >> 2) + 1;
            size_t base = (((size_t)b * 32 + sj2) * 8) * 64 + sl2;
            float M = m_part[base];
            float L = l_part[base];
            for (int cj = 1; cj < nchs; cj++) {
                float mi = m_part[base + (size_t)cj * 64];
                float li = l_part[base + (size_t)cj * 64];
                float mn = fmaxf(M, mi);
                L = L * EXP2(M - mn) + li * EXP2(mi - mn);
                M = mn;
            }
            float2 ml; ml.x = M; ml.y = 1.0f / L;
            mlbuf[tid] = ml;
        }
    }

    int t_base = tj * 64 + wave * 16;

    // A fragments: wave's 16 q-rows (fp16); t&15 == c15
    half8 qa[4];
    {
        int t = t_base + c15;
        const unsigned short* qr = qf + ((size_t)(b * Tn + t)) * Hn;
#pragma unroll
        for (int st = 0; st < 4; st++) {
            int off = ((st * 4 + kg) ^ c15) * 8;
            qa[st] = *(const half8*)(qr + off);
        }
    }
    float4v oacc[8];
#pragma unroll
    for (int i = 0; i < 8; i++) oacc[i] = (float4v)0.0f;

    auto stage = [&](int c) {
        const unsigned short* Kf = kf + ((size_t)b * Tn + c * 32) * Hn;
        const unsigned short* Vv = vtt + ((size_t)b * 64 + c) * (128 * 32);
        int lo8 = lane * 8;
#pragma unroll
        for (int i = 0; i < 4; i++) {
            int ch = wave * 4 + i;   // 0..15
            const unsigned short* g;
            unsigned short* ld;
            if (ch < 8) { g = Kf + ch * 512;       ld = lds + ch * 512; }
            else        { g = Vv + (ch - 8) * 512; ld = lds + 4096 + (ch - 8) * 512; }
            gll16(g + lo8, ld + lo8);
        }
    };

    for (int c = cs; c < ce; c++) {
        stage(c);
        __syncthreads();   // stage complete (also orders mlbuf on iter 0)
#pragma unroll
        for (int half = 0; half < 2; half++) {
            int s16 = c * 32 + half * 16;
            int sl = half * 16 + c15;
            float4v a1 = (float4v)0.0f;
#pragma unroll
            for (int st = 0; st < 4; st++) {
                // swizzled block ((st*4+kg) ^ (s&15)); s&15 == c15
                int off = sl * 128 + ((st * 4 + kg) ^ c15) * 8;
                half8 bh = *(const half8*)(lds + off);
                a1 = MFMA16F(qa[st], bh, a1);
            }
            float2 mlv = mlbuf[(c - cs) * 32 + sl];    // fused (m2, il)
#pragma unroll
            for (int r = 0; r < 4; r++) {
                int t = t_base + kg * 4 + r;
                float attv = a1[r] * SQRTH_LOG2E;      // base-2 domain
                // clamp: att <= column max for true data (ULP-exact safety)
                float earg = fminf(attv - mlv.x, 0.0f);
                float p = (t >= s16 + c15) ? EXP2(earg) * mlv.y : 0.0f;
                pbuf[wave][kg * 4 + r][c15 + half * 16] = f2bf(p);
            }
        }
        // C-layout -> A-layout via LDS (wave-internal, DS pipe in-order)
        short8 pa = *(const short8*)&pbuf[wave][c15][kg * 8];
#pragma unroll
        for (int nt = 0; nt < 8; nt++) {
            // vtt row h = nt*16+c15; swizzled block kg ^ ((h>>1)&3),
            // (h>>1)&3 == (c15>>1)&3 since nt*16 is a multiple of 8 in h>>1
            int voff = (nt * 16 + c15) * 32 + ((kg ^ ((c15 >> 1) & 3)) * 8);
            short8 vb = *(const short8*)(lds + 4096 + voff);
            oacc[nt] = MFMA16(pa, vb, oacc[nt]);
        }
        __syncthreads();   // all reads done before next stage overwrites
    }
    // partial tile store: part[b][tj][ci][t_local 64][h 128]
    float* po = part_out + ((((size_t)b * 32 + tj) * 8 + ci) * 64) * 128;
#pragma unroll
    for (int nt = 0; nt < 8; nt++) {
        int h = nt * 16 + c15;
#pragma unroll
        for (int r = 0; r < 4; r++) {
            int tl = wave * 16 + kg * 4 + r;
            po[(size_t)tl * 128 + h] = oacc[nt][r];
        }
    }
}

// ---------------------------------------------------------------------------
// Kernel 3b: sum output partials -> out. 2M floats, float4 loads/stores.
// ---------------------------------------------------------------------------
__global__ __launch_bounds__(256) void out_combine_kernel(
    const float* __restrict__ part_out, float* __restrict__ out)
{
    int g = blockIdx.x * 256 + threadIdx.x;   // 0..524287 (float4 units)
    int h4 = g & 31;
    int t = (g >> 5) & 2047;
    int b = g >> 16;
    int tj = t >> 6, tl = t & 63;
    int nch = (tj >> 2) + 1;
    const float4v* p = (const float4v*)(part_out
        + ((((size_t)b * 32 + tj) * 8) * 64 + tl) * 128) + h4;
    float4v acc = p[0];
    for (int ci = 1; ci < nch; ci++) acc += p[(size_t)ci * 2048];  // slot = 8192 floats
    *((float4v*)(out + ((size_t)b * Tn + t) * Hn) + h4) = acc;
}

// ---------------------------------------------------------------------------
extern "C" void kernel_launch(void* const* d_in, const int* in_sizes, int n_in,
                              void* d_out, int out_size, void* d_ws, size_t ws_size,
                              hipStream_t stream)
{
    (void)in_sizes; (void)n_in; (void)out_size; (void)ws_size;
    const float* x  = (const float*)d_in[0];
    const float* Wk = (const float*)d_in[1];
    const float* Wq = (const float*)d_in[2];
    const float* Wv = (const float*)d_in[3];
    float* out = (float*)d_out;

    const size_t NQ = (size_t)Bn * Tn * Hn;        // 2,097,152
    const size_t NX = (size_t)Bn * Tn * En;        // 16,777,216
    unsigned short* qf  = (unsigned short*)d_ws;   // fp16 q
    unsigned short* qlo = qf + NQ;                 // unused (kept layout)
    unsigned short* kf  = qlo + NQ;                // fp16 k
    unsigned short* klo = kf + NQ;                 // unused (kept layout)
    unsigned short* vtt  = klo + NQ;
    unsigned short* xt   = vtt + NQ;               // fp16 xt
    unsigned short* xt_lo = xt + NX;               // unused (kept layout)
    unsigned short* wtt  = xt_lo + NX;             // fp16 wtt
    unsigned short* wtt_lo = wtt + (size_t)3 * Hn * En;  // unused region
    // total ws use: ~89.4 MB — identical extent to the validated R7 layout

    // Dead-after-proj aliases:
    //  part_out = xt region: 8*32*8*64*128 fp32 = 67.1 MB == sizeof(xt+xt_lo)
    //  m_part/l_part = wtt regions: 8*32*8*64 fp32 = 512 KB each (<= 768 KB)
    float* part_out = (float*)xt;
    float* m_part   = (float*)wtt;
    float* l_part   = (float*)wtt_lo;

    prep_kernel<<<dim3(8384), 256, 0, stream>>>(x, Wq, Wk, Wv, xt, wtt);
    proj_kernel<<<dim3(256, 3), 256, 0, stream>>>(xt, wtt, qf, kf, vtt);
    stats_part_kernel<<<dim3(Bn, 144), 256, 0, stream>>>(qf, kf, m_part, l_part);
    out_part_kernel<<<dim3(Bn, 144), 256, 0, stream>>>(qf, kf, vtt,
                                                       m_part, l_part, part_out);
    out_combine_kernel<<<dim3(2048), 256, 0, stream>>>(part_out, out);
}